// Round 1
// baseline (1200.687 us; speedup 1.0000x reference)
//
#include <hip/hip_runtime.h>

typedef __attribute__((ext_vector_type(8))) short short8;
typedef __attribute__((ext_vector_type(2))) short short2v;
typedef __attribute__((ext_vector_type(4))) float float4v;
typedef __attribute__((ext_vector_type(2))) float float2v;

#define Hh 128
#define Ss 200
#define Ee 64
#define BR 8       // batch rows per block (GRU kernel) -> 512 blocks = 2 blocks/CU
#define TPB3 512   // 8 waves

#if defined(__has_builtin) && __has_builtin(__builtin_amdgcn_exp2f)
#define EXP2F(x) __builtin_amdgcn_exp2f(x)
#else
#define EXP2F(x) exp2f(x)
#endif
#if defined(__has_builtin) && __has_builtin(__builtin_amdgcn_rcpf)
#define RCPF(x) __builtin_amdgcn_rcpf(x)
#else
#define RCPF(x) (1.0f / (x))
#endif

#define LOG2E 1.442695040888963f

__device__ __forceinline__ float fsig(float z) {
    return RCPF(1.0f + EXP2F(-LOG2E * z));       // 1/(1+e^-z), native exp/rcp
}
__device__ __forceinline__ float ftanh(float z) {
    return 1.0f - 2.0f * RCPF(1.0f + EXP2F(2.0f * LOG2E * z)); // saturates correctly at +-inf
}

// round-to-nearest-even float -> bf16 bits
__device__ __forceinline__ short f2bf(float f) {
    unsigned u = __float_as_uint(f);
    u += 0x7FFFu + ((u >> 16) & 1u);
    return (short)(u >> 16);
}
__device__ __forceinline__ float bf2f(short s) {
    return __uint_as_float(((unsigned)(unsigned short)s) << 16);
}

// ---------------- Kernel 1: v = W_bil@tgt (fused) + logits + softmax -> att[B,S] ----------------
// Coalesced: 16-lane group per s-row; a wave covers 4 consecutive rows = 2KB contiguous.
__global__ __launch_bounds__(256) void attn_kernel(
    const float* __restrict__ x, const float* __restrict__ tgt,
    const float* __restrict__ Wb, float* __restrict__ att)
{
    __shared__ float tgS[Ee];
    __shared__ float vS[Hh];
    __shared__ float lg[Ss];
    __shared__ float redM, redZ;

    int tid = threadIdx.x;
    int b = blockIdx.x;

    if (tid < Ee) tgS[tid] = tgt[(size_t)b * Ee + tid];
    __syncthreads();

    // v[h] = sum_e Wb[h,e] * tgt[b,e]   (Wb is L2-hot: 32KB read by all blocks)
    if (tid < Hh) {
        const float* wr = Wb + (size_t)tid * Ee;
        float acc = 0.f;
        #pragma unroll
        for (int e4 = 0; e4 < Ee / 4; ++e4) {
            float4v wv = *(const float4v*)&wr[e4 * 4];
            float4v tv = *(const float4v*)&tgS[e4 * 4];
            acc += wv.x * tv.x + wv.y * tv.y + wv.z * tv.z + wv.w * tv.w;
        }
        vS[tid] = acc;
    }
    __syncthreads();

    int g = tid >> 4, l16 = tid & 15;      // 16 groups of 16 lanes
    float v0[8];
    #pragma unroll
    for (int j = 0; j < 8; ++j) v0[j] = vS[l16 * 8 + j];

    for (int s = g; s < Ss; s += 16) {
        const float* xr = x + ((size_t)b * Ss + s) * Hh + l16 * 8;
        float4v x0 = *(const float4v*)xr;
        float4v x1 = *(const float4v*)(xr + 4);
        float d = x0.x * v0[0] + x0.y * v0[1] + x0.z * v0[2] + x0.w * v0[3]
                + x1.x * v0[4] + x1.y * v0[5] + x1.z * v0[6] + x1.w * v0[7];
        d += __shfl_xor(d, 8);
        d += __shfl_xor(d, 4);
        d += __shfl_xor(d, 2);
        d += __shfl_xor(d, 1);
        if (l16 == 0) lg[s] = d;
    }
    __syncthreads();

    if (tid < 64) {
        float m = -1e30f;
        for (int s = tid; s < Ss; s += 64) m = fmaxf(m, lg[s]);
        #pragma unroll
        for (int off = 32; off > 0; off >>= 1) m = fmaxf(m, __shfl_xor(m, off));
        float z = 0.f;
        for (int s = tid; s < Ss; s += 64) z += EXP2F((lg[s] - m) * LOG2E);
        #pragma unroll
        for (int off = 32; off > 0; off >>= 1) z += __shfl_xor(z, off);
        if (tid == 0) { redM = m; redZ = RCPF(z); }
    }
    __syncthreads();

    if (tid < Ss)
        att[(size_t)b * Ss + tid] = EXP2F((lg[tid] - redM) * LOG2E) * redZ;
}

// ---------------- Kernel 2: attention-gated GRU scan, weights register-resident ----------------
// BR=8: grid = 512 blocks -> 2 blocks/CU (LDS 27.7KB, VGPR capped 128 by launch_bounds(512,4)).
// MFMA A-rows 8..15 are zero padding; epilogues guarded to quad<2 (rows 0..7).
__global__ __launch_bounds__(TPB3, 4) void gru_kernel(
    const float* __restrict__ x, const float* __restrict__ att,
    const float* __restrict__ Wxu, const float* __restrict__ Whu, const float* __restrict__ bu,
    const float* __restrict__ Wxr, const float* __restrict__ Whr, const float* __restrict__ br,
    const float* __restrict__ Wxc, const float* __restrict__ Whc, const float* __restrict__ bc,
    float* __restrict__ out)
{
    __shared__ __align__(16) short xh[16][264];   // rows 0-7: [x(128) | h(128)] bf16 (+8 pad); rows 8-15 zero
    __shared__ __align__(16) short rhs[16][136];  // rows 0-7: r*h bf16 (+8 pad); rows 8-15 zero
    __shared__ __align__(16) float G1[BR][132];   // u gate fp32 (+4 pad)
    __shared__ __align__(16) float C2[BR][132];   // candidate fp32 (+4 pad)
    __shared__ float attS[BR][Ss];

    int tid = threadIdx.x;
    int wave = tid >> 6, lane = tid & 63;
    int quad = lane >> 4, l16 = lane & 15;
    int b0 = blockIdx.x * BR;

    // ---- one-time: weights -> bf16 MFMA B-fragments in registers ----
    // phase1: waves 0-3 own u cols, waves 4-7 own r cols; K=256 = [x|h]
    // phase2: wave w owns c cols w*16..+15; K=256 = [x|r*h]
    short8 W1[2][8];
    short8 W2[8];
    #pragma unroll
    for (int t = 0; t < 2; ++t) {
        int fullcol = wave * 32 + t * 16 + l16;           // 0..255
        const float* Wx = (fullcol < 128) ? Wxu : Wxr;
        const float* Wh = (fullcol < 128) ? Whu : Whr;
        int n = fullcol & 127;
        #pragma unroll
        for (int q = 0; q < 8; ++q) {
            short8 f;
            #pragma unroll
            for (int j = 0; j < 8; ++j) {
                int k = q * 32 + quad * 8 + j;            // 0..255
                float wv = (k < 128) ? Wx[k * Hh + n] : Wh[(k - 128) * Hh + n];
                f[j] = f2bf(wv);
            }
            W1[t][q] = f;
        }
    }
    {
        int n2 = wave * 16 + l16;
        #pragma unroll
        for (int q = 0; q < 8; ++q) {
            short8 f;
            #pragma unroll
            for (int j = 0; j < 8; ++j) {
                int k = q * 32 + quad * 8 + j;
                float wv = (k < 128) ? Wxc[k * Hh + n2] : Whc[(k - 128) * Hh + n2];
                f[j] = f2bf(wv);
            }
            W2[q] = f;
        }
    }
    float b1[2];
    #pragma unroll
    for (int t = 0; t < 2; ++t) {
        int fullcol = wave * 32 + t * 16 + l16;
        b1[t] = (fullcol < 128) ? bu[fullcol] : br[fullcol - 128];
    }
    float b2 = bc[wave * 16 + l16];

    // ---- zero dead MFMA rows (8..15) once, and h0 rows 0..7 ----
    for (int i = tid; i < 8 * 264; i += TPB3) xh[8 + i / 264][i % 264] = 0;
    for (int i = tid; i < 8 * 136; i += TPB3) rhs[8 + i / 136][i % 136] = 0;
    for (int i = tid; i < 8 * 128; i += TPB3) xh[i >> 7][Hh + (i & 127)] = 0;

    // ---- preload this block's attention weights ----
    for (int i = tid; i < BR * Ss; i += TPB3) {
        int rr = i / Ss, sc = i % Ss;
        attS[rr][sc] = att[(size_t)(b0 + rr) * Ss + sc];
    }

    // ---- updater mapping: thread owns (urow, 2 consecutive h columns) ----
    int urow = tid >> 6;            // 0..7 (== wave)
    int uc = (tid & 63) * 2;        // 0,2,...,126
    float hreg[2] = {0.f, 0.f};

    const float* xrow = x + (size_t)(b0 + urow) * Ss * Hh + uc;
    float2v xv = *(const float2v*)xrow;   // t=0
    float2v xvn = xv;

    #pragma unroll 1
    for (int t = 0; t < Ss; ++t) {
        // stage x_t -> xh (bf16)
        {
            short2v xs;
            xs[0] = f2bf(xv.x);
            xs[1] = f2bf(xv.y);
            *(short2v*)&xh[urow][uc] = xs;
        }
        // prefetch x_{t+1} NOW: hiding window = the whole step
        if (t + 1 < Ss) xvn = *(const float2v*)&xrow[(size_t)(t + 1) * Hh];
        __syncthreads();   // A: x + h staged

        // phase 1: pre_u / pre_r = [x|h] @ [Wx*;Wh*]
        float4v a0 = {0.f, 0.f, 0.f, 0.f}, a1 = {0.f, 0.f, 0.f, 0.f};
        #pragma unroll
        for (int q = 0; q < 8; ++q) {
            short8 af = *(const short8*)&xh[l16][q * 32 + quad * 8];
            a0 = __builtin_amdgcn_mfma_f32_16x16x32_bf16(af, W1[0][q], a0, 0, 0, 0);
            a1 = __builtin_amdgcn_mfma_f32_16x16x32_bf16(af, W1[1][q], a1, 0, 0, 0);
        }
        if (quad < 2) {        // only output rows 0..7 are real
            if (wave < 4) {
                // u gates -> G1
                int c0 = wave * 32 + l16;
                #pragma unroll
                for (int r = 0; r < 4; ++r) {
                    int rr = quad * 4 + r;
                    G1[rr][c0]      = fsig(a0[r] + b1[0]);
                    G1[rr][c0 + 16] = fsig(a1[r] + b1[1]);
                }
            } else {
                // r gates: compute r*h directly (h as bf16 from xh) -> rhs
                int c0 = (wave - 4) * 32 + l16;
                #pragma unroll
                for (int r = 0; r < 4; ++r) {
                    int rr = quad * 4 + r;
                    float r0 = fsig(a0[r] + b1[0]);
                    float r1 = fsig(a1[r] + b1[1]);
                    float h0 = bf2f(xh[rr][Hh + c0]);
                    float h1 = bf2f(xh[rr][Hh + c0 + 16]);
                    rhs[rr][c0]      = f2bf(r0 * h0);
                    rhs[rr][c0 + 16] = f2bf(r1 * h1);
                }
            }
        }
        __syncthreads();   // B: gates + r*h ready

        // phase 2: pre_c = [x | r*h] @ [Wxc;Whc], tanh -> C2
        float4v a2 = {0.f, 0.f, 0.f, 0.f};
        #pragma unroll
        for (int q = 0; q < 4; ++q) {
            short8 af = *(const short8*)&xh[l16][q * 32 + quad * 8];
            a2 = __builtin_amdgcn_mfma_f32_16x16x32_bf16(af, W2[q], a2, 0, 0, 0);
        }
        #pragma unroll
        for (int q = 0; q < 4; ++q) {
            short8 af = *(const short8*)&rhs[l16][q * 32 + quad * 8];
            a2 = __builtin_amdgcn_mfma_f32_16x16x32_bf16(af, W2[q + 4], a2, 0, 0, 0);
        }
        if (quad < 2) {
            int c0 = wave * 16 + l16;
            #pragma unroll
            for (int r = 0; r < 4; ++r)
                C2[quad * 4 + r][c0] = ftanh(a2[r] + b2);
        }
        __syncthreads();   // C: candidate ready

        // h update (fp32 master in registers), restage h as bf16
        {
            float a = attS[urow][t];
            float2v g = *(const float2v*)&G1[urow][uc];
            float2v c = *(const float2v*)&C2[urow][uc];
            short2v hv;
            float au0 = a * g.x;
            hreg[0] = (1.f - au0) * hreg[0] + au0 * c.x;
            hv[0] = f2bf(hreg[0]);
            float au1 = a * g.y;
            hreg[1] = (1.f - au1) * hreg[1] + au1 * c.y;
            hv[1] = f2bf(hreg[1]);
            *(short2v*)&xh[urow][Hh + uc] = hv;
        }
        xv = xvn;
    }

    // final h -> out[B,H]
    float2v o;
    o.x = hreg[0];
    o.y = hreg[1];
    *(float2v*)&out[(size_t)(b0 + urow) * Hh + uc] = o;
}

extern "C" void kernel_launch(void* const* d_in, const int* in_sizes, int n_in,
                              void* d_out, int out_size, void* d_ws, size_t ws_size,
                              hipStream_t stream) {
    const float* x   = (const float*)d_in[0];   // [B,S,H]
    const float* tgt = (const float*)d_in[1];   // [B,E]
    const float* Wb  = (const float*)d_in[2];   // [H,E]
    const float* Wxu = (const float*)d_in[3];
    const float* Whu = (const float*)d_in[4];
    const float* bu  = (const float*)d_in[5];
    const float* Wxr = (const float*)d_in[6];
    const float* Whr = (const float*)d_in[7];
    const float* br  = (const float*)d_in[8];
    const float* Wxc = (const float*)d_in[9];
    const float* Whc = (const float*)d_in[10];
    const float* bc  = (const float*)d_in[11];
    float* out = (float*)d_out;

    const int B = in_sizes[1] / Ee;             // 4096
    float* att = (float*)d_ws;                  // [B,S] fp32

    attn_kernel<<<B, 256, 0, stream>>>(x, tgt, Wb, att);
    gru_kernel<<<B / BR, TPB3, 0, stream>>>(x, att, Wxu, Whu, bu,
                                            Wxr, Whr, br, Wxc, Whc, bc, out);
}

// Round 3
// 1111.095 us; speedup vs baseline: 1.0806x; 1.0806x over previous
//
#include <hip/hip_runtime.h>

typedef __attribute__((ext_vector_type(8))) short short8;
typedef __attribute__((ext_vector_type(2))) short short2v;
typedef __attribute__((ext_vector_type(4))) float float4v;
typedef __attribute__((ext_vector_type(2))) float float2v;

#define Hh 128
#define Ss 200
#define Ee 64
#define BR 8       // batch rows per block (GRU kernel) -> 512 blocks = 2 blocks/CU
#define TPB3 512   // 8 waves

#if defined(__has_builtin) && __has_builtin(__builtin_amdgcn_exp2f)
#define EXP2F(x) __builtin_amdgcn_exp2f(x)
#else
#define EXP2F(x) exp2f(x)
#endif
#if defined(__has_builtin) && __has_builtin(__builtin_amdgcn_rcpf)
#define RCPF(x) __builtin_amdgcn_rcpf(x)
#else
#define RCPF(x) (1.0f / (x))
#endif

#define LOG2E 1.442695040888963f

__device__ __forceinline__ float fsig(float z) {
    return RCPF(1.0f + EXP2F(-LOG2E * z));       // 1/(1+e^-z), native exp/rcp
}
__device__ __forceinline__ float ftanh(float z) {
    return 1.0f - 2.0f * RCPF(1.0f + EXP2F(2.0f * LOG2E * z)); // saturates correctly at +-inf
}

// round-to-nearest-even float -> bf16 bits
__device__ __forceinline__ short f2bf(float f) {
    unsigned u = __float_as_uint(f);
    u += 0x7FFFu + ((u >> 16) & 1u);
    return (short)(u >> 16);
}
__device__ __forceinline__ float bf2f(short s) {
    return __uint_as_float(((unsigned)(unsigned short)s) << 16);
}

// ---------------- Kernel 1: v = W_bil@tgt (fused) + logits + softmax -> att[B,S] ----------------
// Coalesced: 16-lane group per s-row; a wave covers 4 consecutive rows = 2KB contiguous.
__global__ __launch_bounds__(256) void attn_kernel(
    const float* __restrict__ x, const float* __restrict__ tgt,
    const float* __restrict__ Wb, float* __restrict__ att)
{
    __shared__ float tgS[Ee];
    __shared__ float vS[Hh];
    __shared__ float lg[Ss];
    __shared__ float redM, redZ;

    int tid = threadIdx.x;
    int b = blockIdx.x;

    if (tid < Ee) tgS[tid] = tgt[(size_t)b * Ee + tid];
    __syncthreads();

    // v[h] = sum_e Wb[h,e] * tgt[b,e]   (Wb is L2-hot: 32KB read by all blocks)
    if (tid < Hh) {
        const float* wr = Wb + (size_t)tid * Ee;
        float acc = 0.f;
        #pragma unroll
        for (int e4 = 0; e4 < Ee / 4; ++e4) {
            float4v wv = *(const float4v*)&wr[e4 * 4];
            float4v tv = *(const float4v*)&tgS[e4 * 4];
            acc += wv.x * tv.x + wv.y * tv.y + wv.z * tv.z + wv.w * tv.w;
        }
        vS[tid] = acc;
    }
    __syncthreads();

    int g = tid >> 4, l16 = tid & 15;      // 16 groups of 16 lanes
    float v0[8];
    #pragma unroll
    for (int j = 0; j < 8; ++j) v0[j] = vS[l16 * 8 + j];

    for (int s = g; s < Ss; s += 16) {
        const float* xr = x + ((size_t)b * Ss + s) * Hh + l16 * 8;
        float4v x0 = *(const float4v*)xr;
        float4v x1 = *(const float4v*)(xr + 4);
        float d = x0.x * v0[0] + x0.y * v0[1] + x0.z * v0[2] + x0.w * v0[3]
                + x1.x * v0[4] + x1.y * v0[5] + x1.z * v0[6] + x1.w * v0[7];
        d += __shfl_xor(d, 8);
        d += __shfl_xor(d, 4);
        d += __shfl_xor(d, 2);
        d += __shfl_xor(d, 1);
        if (l16 == 0) lg[s] = d;
    }
    __syncthreads();

    if (tid < 64) {
        float m = -1e30f;
        for (int s = tid; s < Ss; s += 64) m = fmaxf(m, lg[s]);
        #pragma unroll
        for (int off = 32; off > 0; off >>= 1) m = fmaxf(m, __shfl_xor(m, off));
        float z = 0.f;
        for (int s = tid; s < Ss; s += 64) z += EXP2F((lg[s] - m) * LOG2E);
        #pragma unroll
        for (int off = 32; off > 0; off >>= 1) z += __shfl_xor(z, off);
        if (tid == 0) { redM = m; redZ = RCPF(z); }
    }
    __syncthreads();

    if (tid < Ss)
        att[(size_t)b * Ss + tid] = EXP2F((lg[tid] - redM) * LOG2E) * redZ;
}

// ---------------- Kernel 2: attention-gated GRU scan, weights register-resident ----------------
// BR=8: grid = 512 blocks -> 2 blocks/CU (LDS 27.7KB).
// __launch_bounds__(512, 2): hipcc uses CUDA min-BLOCKS-per-CU semantics (R1 evidence:
// arg=4 -> 32 waves/CU -> 64-VGPR cap -> weight spill, WRITE_SIZE 132MB). arg=2 ->
// 16 waves/CU -> 128-VGPR cap; natural allocation ~116 fits, weights stay in registers.
// MFMA A-rows 8..15 are zero padding; epilogues guarded to quad<2 (rows 0..7).
__global__ __launch_bounds__(TPB3, 2) void gru_kernel(
    const float* __restrict__ x, const float* __restrict__ att,
    const float* __restrict__ Wxu, const float* __restrict__ Whu, const float* __restrict__ bu,
    const float* __restrict__ Wxr, const float* __restrict__ Whr, const float* __restrict__ br,
    const float* __restrict__ Wxc, const float* __restrict__ Whc, const float* __restrict__ bc,
    float* __restrict__ out)
{
    __shared__ __align__(16) short xh[16][264];   // rows 0-7: [x(128) | h(128)] bf16 (+8 pad); rows 8-15 zero
    __shared__ __align__(16) short rhs[16][136];  // rows 0-7: r*h bf16 (+8 pad); rows 8-15 zero
    __shared__ __align__(16) float G1[BR][132];   // u gate fp32 (+4 pad)
    __shared__ __align__(16) float C2[BR][132];   // candidate fp32 (+4 pad)
    __shared__ float attS[BR][Ss];

    int tid = threadIdx.x;
    int wave = tid >> 6, lane = tid & 63;
    int quad = lane >> 4, l16 = lane & 15;
    int b0 = blockIdx.x * BR;

    // ---- one-time: weights -> bf16 MFMA B-fragments in registers ----
    // phase1: waves 0-3 own u cols, waves 4-7 own r cols; K=256 = [x|h]
    // phase2: wave w owns c cols w*16..+15; K=256 = [x|r*h]
    short8 W1[2][8];
    short8 W2[8];
    #pragma unroll
    for (int t = 0; t < 2; ++t) {
        int fullcol = wave * 32 + t * 16 + l16;           // 0..255
        const float* Wx = (fullcol < 128) ? Wxu : Wxr;
        const float* Wh = (fullcol < 128) ? Whu : Whr;
        int n = fullcol & 127;
        #pragma unroll
        for (int q = 0; q < 8; ++q) {
            short8 f;
            #pragma unroll
            for (int j = 0; j < 8; ++j) {
                int k = q * 32 + quad * 8 + j;            // 0..255
                float wv = (k < 128) ? Wx[k * Hh + n] : Wh[(k - 128) * Hh + n];
                f[j] = f2bf(wv);
            }
            W1[t][q] = f;
        }
    }
    {
        int n2 = wave * 16 + l16;
        #pragma unroll
        for (int q = 0; q < 8; ++q) {
            short8 f;
            #pragma unroll
            for (int j = 0; j < 8; ++j) {
                int k = q * 32 + quad * 8 + j;
                float wv = (k < 128) ? Wxc[k * Hh + n2] : Whc[(k - 128) * Hh + n2];
                f[j] = f2bf(wv);
            }
            W2[q] = f;
        }
    }
    float b1[2];
    #pragma unroll
    for (int t = 0; t < 2; ++t) {
        int fullcol = wave * 32 + t * 16 + l16;
        b1[t] = (fullcol < 128) ? bu[fullcol] : br[fullcol - 128];
    }
    float b2 = bc[wave * 16 + l16];

    // ---- zero dead MFMA rows (8..15) once, and h0 rows 0..7 ----
    for (int i = tid; i < 8 * 264; i += TPB3) xh[8 + i / 264][i % 264] = 0;
    for (int i = tid; i < 8 * 136; i += TPB3) rhs[8 + i / 136][i % 136] = 0;
    for (int i = tid; i < 8 * 128; i += TPB3) xh[i >> 7][Hh + (i & 127)] = 0;

    // ---- preload this block's attention weights ----
    for (int i = tid; i < BR * Ss; i += TPB3) {
        int rr = i / Ss, sc = i % Ss;
        attS[rr][sc] = att[(size_t)(b0 + rr) * Ss + sc];
    }

    // ---- updater mapping: thread owns (urow, 2 consecutive h columns) ----
    int urow = tid >> 6;            // 0..7 (== wave)
    int uc = (tid & 63) * 2;        // 0,2,...,126
    float hreg[2] = {0.f, 0.f};

    const float* xrow = x + (size_t)(b0 + urow) * Ss * Hh + uc;
    float2v xv = *(const float2v*)xrow;   // t=0
    float2v xvn = xv;

    #pragma unroll 1
    for (int t = 0; t < Ss; ++t) {
        // stage x_t -> xh (bf16)
        {
            short2v xs;
            xs[0] = f2bf(xv.x);
            xs[1] = f2bf(xv.y);
            *(short2v*)&xh[urow][uc] = xs;
        }
        // prefetch x_{t+1} NOW: hiding window = the whole step
        if (t + 1 < Ss) xvn = *(const float2v*)&xrow[(size_t)(t + 1) * Hh];
        __syncthreads();   // A: x + h staged

        // phase 1: pre_u / pre_r = [x|h] @ [Wx*;Wh*]
        float4v a0 = {0.f, 0.f, 0.f, 0.f}, a1 = {0.f, 0.f, 0.f, 0.f};
        #pragma unroll
        for (int q = 0; q < 8; ++q) {
            short8 af = *(const short8*)&xh[l16][q * 32 + quad * 8];
            a0 = __builtin_amdgcn_mfma_f32_16x16x32_bf16(af, W1[0][q], a0, 0, 0, 0);
            a1 = __builtin_amdgcn_mfma_f32_16x16x32_bf16(af, W1[1][q], a1, 0, 0, 0);
        }
        if (quad < 2) {        // only output rows 0..7 are real
            if (wave < 4) {
                // u gates -> G1
                int c0 = wave * 32 + l16;
                #pragma unroll
                for (int r = 0; r < 4; ++r) {
                    int rr = quad * 4 + r;
                    G1[rr][c0]      = fsig(a0[r] + b1[0]);
                    G1[rr][c0 + 16] = fsig(a1[r] + b1[1]);
                }
            } else {
                // r gates: compute r*h directly (h as bf16 from xh) -> rhs
                int c0 = (wave - 4) * 32 + l16;
                #pragma unroll
                for (int r = 0; r < 4; ++r) {
                    int rr = quad * 4 + r;
                    float r0 = fsig(a0[r] + b1[0]);
                    float r1 = fsig(a1[r] + b1[1]);
                    float h0 = bf2f(xh[rr][Hh + c0]);
                    float h1 = bf2f(xh[rr][Hh + c0 + 16]);
                    rhs[rr][c0]      = f2bf(r0 * h0);
                    rhs[rr][c0 + 16] = f2bf(r1 * h1);
                }
            }
        }
        __syncthreads();   // B: gates + r*h ready

        // phase 2: pre_c = [x | r*h] @ [Wxc;Whc], tanh -> C2
        float4v a2 = {0.f, 0.f, 0.f, 0.f};
        #pragma unroll
        for (int q = 0; q < 4; ++q) {
            short8 af = *(const short8*)&xh[l16][q * 32 + quad * 8];
            a2 = __builtin_amdgcn_mfma_f32_16x16x32_bf16(af, W2[q], a2, 0, 0, 0);
        }
        #pragma unroll
        for (int q = 0; q < 4; ++q) {
            short8 af = *(const short8*)&rhs[l16][q * 32 + quad * 8];
            a2 = __builtin_amdgcn_mfma_f32_16x16x32_bf16(af, W2[q + 4], a2, 0, 0, 0);
        }
        if (quad < 2) {
            int c0 = wave * 16 + l16;
            #pragma unroll
            for (int r = 0; r < 4; ++r)
                C2[quad * 4 + r][c0] = ftanh(a2[r] + b2);
        }
        __syncthreads();   // C: candidate ready

        // h update (fp32 master in registers), restage h as bf16
        {
            float a = attS[urow][t];
            float2v g = *(const float2v*)&G1[urow][uc];
            float2v c = *(const float2v*)&C2[urow][uc];
            short2v hv;
            float au0 = a * g.x;
            hreg[0] = (1.f - au0) * hreg[0] + au0 * c.x;
            hv[0] = f2bf(hreg[0]);
            float au1 = a * g.y;
            hreg[1] = (1.f - au1) * hreg[1] + au1 * c.y;
            hv[1] = f2bf(hreg[1]);
            *(short2v*)&xh[urow][Hh + uc] = hv;
        }
        xv = xvn;
    }

    // final h -> out[B,H]
    float2v o;
    o.x = hreg[0];
    o.y = hreg[1];
    *(float2v*)&out[(size_t)(b0 + urow) * Hh + uc] = o;
}

extern "C" void kernel_launch(void* const* d_in, const int* in_sizes, int n_in,
                              void* d_out, int out_size, void* d_ws, size_t ws_size,
                              hipStream_t stream) {
    const float* x   = (const float*)d_in[0];   // [B,S,H]
    const float* tgt = (const float*)d_in[1];   // [B,E]
    const float* Wb  = (const float*)d_in[2];   // [H,E]
    const float* Wxu = (const float*)d_in[3];
    const float* Whu = (const float*)d_in[4];
    const float* bu  = (const float*)d_in[5];
    const float* Wxr = (const float*)d_in[6];
    const float* Whr = (const float*)d_in[7];
    const float* br  = (const float*)d_in[8];
    const float* Wxc = (const float*)d_in[9];
    const float* Whc = (const float*)d_in[10];
    const float* bc  = (const float*)d_in[11];
    float* out = (float*)d_out;

    const int B = in_sizes[1] / Ee;             // 4096
    float* att = (float*)d_ws;                  // [B,S] fp32

    attn_kernel<<<B, 256, 0, stream>>>(x, tgt, Wb, att);
    gru_kernel<<<B / BR, TPB3, 0, stream>>>(x, att, Wxu, Whu, bu,
                                            Wxr, Whr, br, Wxc, Whc, bc, out);
}

// Round 4
// 833.566 us; speedup vs baseline: 1.4404x; 1.3329x over previous
//
#include <hip/hip_runtime.h>

typedef __attribute__((ext_vector_type(8))) short short8;
typedef __attribute__((ext_vector_type(4))) short short4v;
typedef __attribute__((ext_vector_type(4))) float float4v;

#define Hh 128
#define Ss 200
#define Ee 64
#define BR 16      // batch rows per block -> grid 256 = 1 block/CU (proven R0 structure)
#define TPB3 512   // 8 waves

#if defined(__has_builtin) && __has_builtin(__builtin_amdgcn_exp2f)
#define EXP2F(x) __builtin_amdgcn_exp2f(x)
#else
#define EXP2F(x) exp2f(x)
#endif
#if defined(__has_builtin) && __has_builtin(__builtin_amdgcn_rcpf)
#define RCPF(x) __builtin_amdgcn_rcpf(x)
#else
#define RCPF(x) (1.0f / (x))
#endif

#define LOG2E 1.442695040888963f

__device__ __forceinline__ float fsig(float z) {
    return RCPF(1.0f + EXP2F(-LOG2E * z));       // 1/(1+e^-z), native exp/rcp
}
__device__ __forceinline__ float ftanh(float z) {
    return 1.0f - 2.0f * RCPF(1.0f + EXP2F(2.0f * LOG2E * z)); // saturates correctly at +-inf
}

// round-to-nearest-even float -> bf16 bits
__device__ __forceinline__ short f2bf(float f) {
    unsigned u = __float_as_uint(f);
    u += 0x7FFFu + ((u >> 16) & 1u);
    return (short)(u >> 16);
}
__device__ __forceinline__ float bf2f(short s) {
    return __uint_as_float(((unsigned)(unsigned short)s) << 16);
}

// ============ Single fused kernel: bilinear attention + softmax + gated-GRU scan ============
// Prologue computes v = Wb@tgt, logits, softmax entirely in-block (attS in LDS),
// eliminating the separate attn dispatch and its HBM pass/overhead.
// Scan is the R0-proven BR=16 structure (308us measured), weights register-resident.
__global__ __launch_bounds__(TPB3) void fused_kernel(
    const float* __restrict__ x, const float* __restrict__ tgt,
    const float* __restrict__ Wb,
    const float* __restrict__ Wxu, const float* __restrict__ Whu, const float* __restrict__ bu,
    const float* __restrict__ Wxr, const float* __restrict__ Whr, const float* __restrict__ br,
    const float* __restrict__ Wxc, const float* __restrict__ Whc, const float* __restrict__ bc,
    float* __restrict__ out)
{
    __shared__ __align__(16) short xh[BR][264];   // [x(128) | h(128)] bf16 (+8 pad)
    __shared__ __align__(16) short rhs[BR][136];  // r*h bf16 (+8 pad)
    __shared__ __align__(16) float G1[BR][132];   // u gate fp32 (+4 pad); prologue scratch: vv[16][128]
    __shared__ __align__(16) float C2[BR][132];   // candidate fp32 (+4 pad); prologue scratch: tg[16][64]
    __shared__ float attS[BR][Ss];                // prologue output: softmaxed attention

    int tid = threadIdx.x;
    int wave = tid >> 6, lane = tid & 63;
    int quad = lane >> 4, l16 = lane & 15;
    int b0 = blockIdx.x * BR;

    // ================= Prologue: attention =================
    float* tg = &C2[0][0];    // [16][64] flat (1024 <= 16*132 floats)
    float* vv = &G1[0][0];    // [16][128] flat (2048 <= 16*132 floats)

    // P0: stage target rows (contiguous 4KB)
    for (int i = tid; i < BR * Ee; i += TPB3) tg[i] = tgt[(size_t)b0 * Ee + i];
    __syncthreads();

    // P1: v[r][h] = Wb[h,:] . tgt[r,:]   (Wb L2-hot across all 256 blocks)
    {
        int h = tid & 127, rq = tid >> 7;          // rq 0..3 -> rows rq*4..rq*4+3
        float acc[4] = {0.f, 0.f, 0.f, 0.f};
        const float* wr = Wb + (size_t)h * Ee;
        #pragma unroll
        for (int e4 = 0; e4 < Ee / 4; ++e4) {
            float4v wv = *(const float4v*)&wr[e4 * 4];
            #pragma unroll
            for (int ro = 0; ro < 4; ++ro) {
                float4v tv = *(const float4v*)&tg[(rq * 4 + ro) * Ee + e4 * 4];
                acc[ro] += wv.x * tv.x + wv.y * tv.y + wv.z * tv.z + wv.w * tv.w;
            }
        }
        #pragma unroll
        for (int ro = 0; ro < 4; ++ro) vv[(rq * 4 + ro) * Hh + h] = acc[ro];
    }
    __syncthreads();

    // P2: logits. Wave w owns rows {2w, 2w+1}. 16-lane group per s-row, 4 s per wave-iter,
    // 8 dwordx4 in flight per lane (128 B) -> BW-bound, coalesced (wave = 2KB contiguous).
    #pragma unroll 1
    for (int rr = 0; rr < 2; ++rr) {
        int r = wave * 2 + rr;
        float vr[8];
        *(float4v*)&vr[0] = *(const float4v*)&vv[r * Hh + l16 * 8];
        *(float4v*)&vr[4] = *(const float4v*)&vv[r * Hh + l16 * 8 + 4];
        const float* xb = x + ((size_t)(b0 + r) * Ss) * Hh + l16 * 8;
        // coverage partitions s exactly: groups {0,1}: 13 iters, {2,3}: 12 iters, all full-4
        for (int s0 = quad * 4; s0 < Ss; s0 += 16) {
            float4v xa[4][2];
            #pragma unroll
            for (int j = 0; j < 4; ++j) {
                const float* xr = xb + (size_t)(s0 + j) * Hh;
                xa[j][0] = *(const float4v*)xr;
                xa[j][1] = *(const float4v*)(xr + 4);
            }
            #pragma unroll
            for (int j = 0; j < 4; ++j) {
                float d = xa[j][0].x * vr[0] + xa[j][0].y * vr[1]
                        + xa[j][0].z * vr[2] + xa[j][0].w * vr[3]
                        + xa[j][1].x * vr[4] + xa[j][1].y * vr[5]
                        + xa[j][1].z * vr[6] + xa[j][1].w * vr[7];
                d += __shfl_xor(d, 8);
                d += __shfl_xor(d, 4);
                d += __shfl_xor(d, 2);
                d += __shfl_xor(d, 1);
                if (l16 == 0) attS[r][s0 + j] = d;
            }
        }
    }
    // P3: softmax per row, fully in-wave (wave wrote its own rows -> no barrier needed before)
    #pragma unroll 1
    for (int rr = 0; rr < 2; ++rr) {
        int r = wave * 2 + rr;
        float vals[4], m = -1e30f;
        #pragma unroll
        for (int i = 0; i < 4; ++i) {
            int s = lane + i * 64;
            vals[i] = (s < Ss) ? attS[r][s] : -1e30f;
            m = fmaxf(m, vals[i]);
        }
        #pragma unroll
        for (int off = 32; off > 0; off >>= 1) m = fmaxf(m, __shfl_xor(m, off));
        float z = 0.f;
        #pragma unroll
        for (int i = 0; i < 4; ++i) {
            int s = lane + i * 64;
            vals[i] = (s < Ss) ? EXP2F((vals[i] - m) * LOG2E) : 0.f;
            z += vals[i];
        }
        #pragma unroll
        for (int off = 32; off > 0; off >>= 1) z += __shfl_xor(z, off);
        float zi = RCPF(z);
        #pragma unroll
        for (int i = 0; i < 4; ++i) {
            int s = lane + i * 64;
            if (s < Ss) attS[r][s] = vals[i] * zi;
        }
    }
    __syncthreads();   // attS final; G1/C2 scratch dead (overwritten each scan step before read)

    // ================= Weights -> bf16 MFMA B-fragments in registers =================
    // phase1: waves 0-3 own u cols, waves 4-7 own r cols; K=256 = [x|h]
    // phase2: wave w owns c cols w*16..+15; K=256 = [x|r*h]
    short8 W1[2][8];
    short8 W2[8];
    #pragma unroll
    for (int t = 0; t < 2; ++t) {
        int fullcol = wave * 32 + t * 16 + l16;           // 0..255
        const float* Wx = (fullcol < 128) ? Wxu : Wxr;
        const float* Wh = (fullcol < 128) ? Whu : Whr;
        int n = fullcol & 127;
        #pragma unroll
        for (int q = 0; q < 8; ++q) {
            short8 f;
            #pragma unroll
            for (int j = 0; j < 8; ++j) {
                int k = q * 32 + quad * 8 + j;            // 0..255
                float wv = (k < 128) ? Wx[k * Hh + n] : Wh[(k - 128) * Hh + n];
                f[j] = f2bf(wv);
            }
            W1[t][q] = f;
        }
    }
    {
        int n2 = wave * 16 + l16;
        #pragma unroll
        for (int q = 0; q < 8; ++q) {
            short8 f;
            #pragma unroll
            for (int j = 0; j < 8; ++j) {
                int k = q * 32 + quad * 8 + j;
                float wv = (k < 128) ? Wxc[k * Hh + n2] : Whc[(k - 128) * Hh + n2];
                f[j] = f2bf(wv);
            }
            W2[q] = f;
        }
    }
    float b1[2];
    #pragma unroll
    for (int t = 0; t < 2; ++t) {
        int fullcol = wave * 32 + t * 16 + l16;
        b1[t] = (fullcol < 128) ? bu[fullcol] : br[fullcol - 128];
    }
    float b2 = bc[wave * 16 + l16];

    // ================= Scan (R0-proven structure) =================
    // updater mapping: thread owns (urow, 4 consecutive h columns)
    int urow = tid >> 5;            // 0..15
    int uc = (tid & 31) * 4;        // 0,4,...,124
    float hreg[4] = {0.f, 0.f, 0.f, 0.f};
    { short4v z = {0, 0, 0, 0}; *(short4v*)&xh[urow][128 + uc] = z; }   // h0 = 0

    const float* xrow = x + (size_t)(b0 + urow) * Ss * Hh + uc;
    float4v xv = *(const float4v*)&xrow[0];   // t=0
    float4v xvn = xv;

    #pragma unroll 1
    for (int t = 0; t < Ss; ++t) {
        // stage x_t -> xh (bf16)
        {
            short4v xs;
            #pragma unroll
            for (int i = 0; i < 4; ++i) xs[i] = f2bf(xv[i]);
            *(short4v*)&xh[urow][uc] = xs;
        }
        // prefetch x_{t+1} NOW: hiding window = the whole step
        if (t + 1 < Ss) xvn = *(const float4v*)&xrow[(size_t)(t + 1) * Hh];
        __syncthreads();   // A: x + h staged

        // phase 1: pre_u / pre_r = [x|h] @ [Wx*;Wh*]
        float4v a0 = {0.f, 0.f, 0.f, 0.f}, a1 = {0.f, 0.f, 0.f, 0.f};
        #pragma unroll
        for (int q = 0; q < 8; ++q) {
            short8 af = *(const short8*)&xh[l16][q * 32 + quad * 8];
            a0 = __builtin_amdgcn_mfma_f32_16x16x32_bf16(af, W1[0][q], a0, 0, 0, 0);
            a1 = __builtin_amdgcn_mfma_f32_16x16x32_bf16(af, W1[1][q], a1, 0, 0, 0);
        }
        if (wave < 4) {
            // u gates -> G1
            int c0 = wave * 32 + l16;
            #pragma unroll
            for (int r = 0; r < 4; ++r) {
                int rr = quad * 4 + r;
                G1[rr][c0]      = fsig(a0[r] + b1[0]);
                G1[rr][c0 + 16] = fsig(a1[r] + b1[1]);
            }
        } else {
            // r gates: compute r*h directly (h as bf16 from xh) -> rhs
            int c0 = (wave - 4) * 32 + l16;
            #pragma unroll
            for (int r = 0; r < 4; ++r) {
                int rr = quad * 4 + r;
                float r0 = fsig(a0[r] + b1[0]);
                float r1 = fsig(a1[r] + b1[1]);
                float h0 = bf2f(xh[rr][128 + c0]);
                float h1 = bf2f(xh[rr][128 + c0 + 16]);
                rhs[rr][c0]      = f2bf(r0 * h0);
                rhs[rr][c0 + 16] = f2bf(r1 * h1);
            }
        }
        __syncthreads();   // B: gates + r*h ready

        // phase 2: pre_c = [x | r*h] @ [Wxc;Whc], tanh -> C2
        float4v a2 = {0.f, 0.f, 0.f, 0.f};
        #pragma unroll
        for (int q = 0; q < 4; ++q) {
            short8 af = *(const short8*)&xh[l16][q * 32 + quad * 8];
            a2 = __builtin_amdgcn_mfma_f32_16x16x32_bf16(af, W2[q], a2, 0, 0, 0);
        }
        #pragma unroll
        for (int q = 0; q < 4; ++q) {
            short8 af = *(const short8*)&rhs[l16][q * 32 + quad * 8];
            a2 = __builtin_amdgcn_mfma_f32_16x16x32_bf16(af, W2[q + 4], a2, 0, 0, 0);
        }
        {
            int c0 = wave * 16 + l16;
            #pragma unroll
            for (int r = 0; r < 4; ++r)
                C2[quad * 4 + r][c0] = ftanh(a2[r] + b2);
        }
        __syncthreads();   // C: candidate ready

        // h update (fp32 master in registers), restage h as bf16
        {
            float a = attS[urow][t];
            short4v hv;
            #pragma unroll
            for (int i = 0; i < 4; ++i) {
                float u = G1[urow][uc + i];
                float c = C2[urow][uc + i];
                float au = a * u;
                hreg[i] = (1.f - au) * hreg[i] + au * c;
                hv[i] = f2bf(hreg[i]);
            }
            *(short4v*)&xh[urow][128 + uc] = hv;
        }
        xv = xvn;
    }

    // final h -> out[B,H]
    float4v o;
    #pragma unroll
    for (int i = 0; i < 4; ++i) o[i] = hreg[i];
    *(float4v*)&out[(size_t)(b0 + urow) * Hh + uc] = o;
}

extern "C" void kernel_launch(void* const* d_in, const int* in_sizes, int n_in,
                              void* d_out, int out_size, void* d_ws, size_t ws_size,
                              hipStream_t stream) {
    const float* x   = (const float*)d_in[0];   // [B,S,H]
    const float* tgt = (const float*)d_in[1];   // [B,E]
    const float* Wb  = (const float*)d_in[2];   // [H,E]
    const float* Wxu = (const float*)d_in[3];
    const float* Whu = (const float*)d_in[4];
    const float* bu  = (const float*)d_in[5];
    const float* Wxr = (const float*)d_in[6];
    const float* Whr = (const float*)d_in[7];
    const float* br  = (const float*)d_in[8];
    const float* Wxc = (const float*)d_in[9];
    const float* Whc = (const float*)d_in[10];
    const float* bc  = (const float*)d_in[11];
    float* out = (float*)d_out;

    const int B = in_sizes[1] / Ee;             // 4096

    fused_kernel<<<B / BR, TPB3, 0, stream>>>(x, tgt, Wb, Wxu, Whu, bu,
                                              Wxr, Whr, br, Wxc, Whc, bc, out);
}

// Round 5
// 790.193 us; speedup vs baseline: 1.5195x; 1.0549x over previous
//
#include <hip/hip_runtime.h>

typedef __attribute__((ext_vector_type(8))) short short8;
typedef __attribute__((ext_vector_type(4))) short short4v;
typedef __attribute__((ext_vector_type(4))) float float4v;

#define Hh 128
#define Ss 200
#define Ee 64
#define BR 16      // batch rows per block -> grid 256 = 1 block/CU
#define TPB3 512   // 8 waves

#if defined(__has_builtin) && __has_builtin(__builtin_amdgcn_exp2f)
#define EXP2F(x) __builtin_amdgcn_exp2f(x)
#else
#define EXP2F(x) exp2f(x)
#endif
#if defined(__has_builtin) && __has_builtin(__builtin_amdgcn_rcpf)
#define RCPF(x) __builtin_amdgcn_rcpf(x)
#else
#define RCPF(x) (1.0f / (x))
#endif

#define LOG2E 1.442695040888963f

__device__ __forceinline__ float fsig(float z) {
    return RCPF(1.0f + EXP2F(-LOG2E * z));       // 1/(1+e^-z)
}
__device__ __forceinline__ float ftanh(float z) {
    return 1.0f - 2.0f * RCPF(1.0f + EXP2F(2.0f * LOG2E * z));
}

// round-to-nearest-even float -> bf16 bits
__device__ __forceinline__ short f2bf(float f) {
    unsigned u = __float_as_uint(f);
    u += 0x7FFFu + ((u >> 16) & 1u);
    return (short)(u >> 16);
}

// ============ Single fused kernel: bilinear attention + softmax + gated-GRU scan ============
// Scan restructure vs R4 (445us): wave w owns output cols w*16..+15 in BOTH phases, so
// u, c, h live in the SAME thread's registers -> G1/C2 LDS arrays + barrier C eliminated
// (2 barriers/step instead of 3). x is double-buffered in LDS so staging x_{t+1} overlaps
// phase2 reads of x_t. MFMA accumulator chains split 8-deep -> 2x4-deep for latency hiding.
__global__ __launch_bounds__(TPB3) void fused_kernel(
    const float* __restrict__ x, const float* __restrict__ tgt,
    const float* __restrict__ Wb,
    const float* __restrict__ Wxu, const float* __restrict__ Whu, const float* __restrict__ bu,
    const float* __restrict__ Wxr, const float* __restrict__ Whr, const float* __restrict__ br,
    const float* __restrict__ Wxc, const float* __restrict__ Whc, const float* __restrict__ bc,
    float* __restrict__ out)
{
    __shared__ __align__(16) short xarr[2][BR][136];  // x_t bf16, double-buffered (+8 pad)
    __shared__ __align__(16) short harr[BR][136];     // h bf16 (+8 pad)
    __shared__ __align__(16) short rhs[BR][136];      // r*h bf16 (+8 pad)
    __shared__ __align__(16) float attS[Ss][BR];      // att, TRANSPOSED [s][row]

    int tid = threadIdx.x;
    int wave = tid >> 6, lane = tid & 63;
    int quad = lane >> 4, l16 = lane & 15;
    int b0 = blockIdx.x * BR;

    // ================= Prologue: attention =================
    // scratch aliases (dead before scan init, separated by barriers):
    float* vv = (float*)&xarr[0][0][0];   // [16][128] f32 = 8192B <= 8704B (xarr)
    float* tg = (float*)&rhs[0][0];       // [16][64]  f32 = 4096B <= 4352B (rhs)

    // P0: stage target rows (contiguous 4KB)
    for (int i = tid; i < BR * Ee; i += TPB3) tg[i] = tgt[(size_t)b0 * Ee + i];
    __syncthreads();

    // P1: v[r][h] = Wb[h,:] . tgt[r,:]  (Wb L2-hot across all 256 blocks)
    {
        int h = tid & 127, rq = tid >> 7;          // rq 0..3 -> rows rq*4..rq*4+3
        float acc[4] = {0.f, 0.f, 0.f, 0.f};
        const float* wr = Wb + (size_t)h * Ee;
        #pragma unroll
        for (int e4 = 0; e4 < Ee / 4; ++e4) {
            float4v wv = *(const float4v*)&wr[e4 * 4];
            #pragma unroll
            for (int ro = 0; ro < 4; ++ro) {
                float4v tv = *(const float4v*)&tg[(rq * 4 + ro) * Ee + e4 * 4];
                acc[ro] += wv.x * tv.x + wv.y * tv.y + wv.z * tv.z + wv.w * tv.w;
            }
        }
        #pragma unroll
        for (int ro = 0; ro < 4; ++ro) vv[(rq * 4 + ro) * Hh + h] = acc[ro];
    }
    __syncthreads();

    // P2: logits. Wave w owns rows {2w,2w+1}; 16-lane group per s-row (coalesced 2KB/wave).
    #pragma unroll 1
    for (int rr = 0; rr < 2; ++rr) {
        int r = wave * 2 + rr;
        float vr[8];
        *(float4v*)&vr[0] = *(const float4v*)&vv[r * Hh + l16 * 8];
        *(float4v*)&vr[4] = *(const float4v*)&vv[r * Hh + l16 * 8 + 4];
        const float* xb = x + ((size_t)(b0 + r) * Ss) * Hh + l16 * 8;
        for (int s0 = quad * 4; s0 < Ss; s0 += 16) {
            float4v xa[4][2];
            #pragma unroll
            for (int j = 0; j < 4; ++j) {
                const float* xr = xb + (size_t)(s0 + j) * Hh;
                xa[j][0] = *(const float4v*)xr;
                xa[j][1] = *(const float4v*)(xr + 4);
            }
            #pragma unroll
            for (int j = 0; j < 4; ++j) {
                float d = xa[j][0].x * vr[0] + xa[j][0].y * vr[1]
                        + xa[j][0].z * vr[2] + xa[j][0].w * vr[3]
                        + xa[j][1].x * vr[4] + xa[j][1].y * vr[5]
                        + xa[j][1].z * vr[6] + xa[j][1].w * vr[7];
                d += __shfl_xor(d, 8);
                d += __shfl_xor(d, 4);
                d += __shfl_xor(d, 2);
                d += __shfl_xor(d, 1);
                if (l16 == 0) attS[s0 + j][r] = d;   // transposed store
            }
        }
    }
    // P3: softmax per row, fully in-wave (wave wrote its own rows; no barrier needed)
    #pragma unroll 1
    for (int rr = 0; rr < 2; ++rr) {
        int r = wave * 2 + rr;
        float vals[4], m = -1e30f;
        #pragma unroll
        for (int i = 0; i < 4; ++i) {
            int s = lane + i * 64;
            vals[i] = (s < Ss) ? attS[s][r] : -1e30f;
            m = fmaxf(m, vals[i]);
        }
        #pragma unroll
        for (int off = 32; off > 0; off >>= 1) m = fmaxf(m, __shfl_xor(m, off));
        float z = 0.f;
        #pragma unroll
        for (int i = 0; i < 4; ++i) {
            int s = lane + i * 64;
            vals[i] = (s < Ss) ? EXP2F((vals[i] - m) * LOG2E) : 0.f;
            z += vals[i];
        }
        #pragma unroll
        for (int off = 32; off > 0; off >>= 1) z += __shfl_xor(z, off);
        float zi = RCPF(z);
        #pragma unroll
        for (int i = 0; i < 4; ++i) {
            int s = lane + i * 64;
            if (s < Ss) attS[s][r] = vals[i] * zi;
        }
    }
    __syncthreads();   // attS final; vv/tg scratch dead from here

    // ================= Weights -> bf16 MFMA B-fragments in registers =================
    // Wave w owns output cols col = w*16+l16 for u, r AND c (unified mapping).
    int col = wave * 16 + l16;
    short8 W1u[8], W1r[8], W2[8];
    #pragma unroll
    for (int q = 0; q < 8; ++q) {
        short8 fu, fr, fc;
        #pragma unroll
        for (int j = 0; j < 8; ++j) {
            int k = q * 32 + quad * 8 + j;            // 0..255
            float wu = (k < 128) ? Wxu[k * Hh + col] : Whu[(k - 128) * Hh + col];
            float wr_ = (k < 128) ? Wxr[k * Hh + col] : Whr[(k - 128) * Hh + col];
            float wc = (k < 128) ? Wxc[k * Hh + col] : Whc[(k - 128) * Hh + col];
            fu[j] = f2bf(wu);
            fr[j] = f2bf(wr_);
            fc[j] = f2bf(wc);
        }
        W1u[q] = fu; W1r[q] = fr; W2[q] = fc;
    }
    float b1u = bu[col], b1r = br[col], b2v = bc[col];

    // ================= Scan init =================
    // stager mapping: thread stages x for (srow, 4 cols)
    int srow = tid >> 5, scol = (tid & 31) * 4;
    const float* xrow = x + (size_t)(b0 + srow) * Ss * Hh + scol;
    float4v xv = *(const float4v*)xrow;              // t = 0
    {
        short4v xs;
        #pragma unroll
        for (int i = 0; i < 4; ++i) xs[i] = f2bf(xv[i]);
        *(short4v*)&xarr[0][srow][scol] = xs;
    }
    // h0 = 0: this thread owns (rows quad*4+r, col) — covers all 16x128 exactly once
    float hreg[4] = {0.f, 0.f, 0.f, 0.f};
    #pragma unroll
    for (int r = 0; r < 4; ++r) harr[quad * 4 + r][col] = 0;

    float4v xv1 = xv;

    #pragma unroll 1
    for (int t = 0; t < Ss; ++t) {
        __syncthreads();   // A: x_t (+ h_{t-1}) staged
        int par = t & 1;

        // issue x_{t+1} prefetch early (hiding window = phase1)
        if (t + 1 < Ss) xv1 = *(const float4v*)&xrow[(size_t)(t + 1) * Hh];

        // ---- phase 1: pre_u / pre_r for cols w*16..+15; K = [x | h] ----
        float4v a0a = {0.f,0.f,0.f,0.f}, a0b = {0.f,0.f,0.f,0.f};
        float4v a1a = {0.f,0.f,0.f,0.f}, a1b = {0.f,0.f,0.f,0.f};
        #pragma unroll
        for (int q = 0; q < 4; ++q) {
            short8 af = *(const short8*)&xarr[par][l16][q * 32 + quad * 8];
            a0a = __builtin_amdgcn_mfma_f32_16x16x32_bf16(af, W1u[q], a0a, 0, 0, 0);
            a1a = __builtin_amdgcn_mfma_f32_16x16x32_bf16(af, W1r[q], a1a, 0, 0, 0);
        }
        #pragma unroll
        for (int q = 0; q < 4; ++q) {
            short8 af = *(const short8*)&harr[l16][q * 32 + quad * 8];
            a0b = __builtin_amdgcn_mfma_f32_16x16x32_bf16(af, W1u[q + 4], a0b, 0, 0, 0);
            a1b = __builtin_amdgcn_mfma_f32_16x16x32_bf16(af, W1r[q + 4], a1b, 0, 0, 0);
        }
        // epilogue: u stays in registers; r*h -> rhs (h from this thread's fp32 hreg!)
        float ureg[4];
        #pragma unroll
        for (int r = 0; r < 4; ++r) {
            ureg[r] = fsig(a0a[r] + a0b[r] + b1u);
            float rg = fsig(a1a[r] + a1b[r] + b1r);
            rhs[quad * 4 + r][col] = f2bf(rg * hreg[r]);
        }
        __syncthreads();   // B: rhs ready

        // ---- phase 2: pre_c for cols w*16..+15; K = [x | r*h] ----
        float4v a2a = {0.f,0.f,0.f,0.f}, a2b = {0.f,0.f,0.f,0.f};
        #pragma unroll
        for (int q = 0; q < 4; ++q) {
            short8 af = *(const short8*)&xarr[par][l16][q * 32 + quad * 8];
            a2a = __builtin_amdgcn_mfma_f32_16x16x32_bf16(af, W2[q], a2a, 0, 0, 0);
        }
        #pragma unroll
        for (int q = 0; q < 4; ++q) {
            short8 af = *(const short8*)&rhs[l16][q * 32 + quad * 8];
            a2b = __builtin_amdgcn_mfma_f32_16x16x32_bf16(af, W2[q + 4], a2b, 0, 0, 0);
        }
        // epilogue: c, h-update all in-register (u, h already here); restage h bf16
        {
            float4v av = *(const float4v*)&attS[t][quad * 4];   // broadcast, conflict-free
            #pragma unroll
            for (int r = 0; r < 4; ++r) {
                float c = ftanh(a2a[r] + a2b[r] + b2v);
                float au = av[r] * ureg[r];
                hreg[r] = (1.f - au) * hreg[r] + au * c;
                harr[quad * 4 + r][col] = f2bf(hreg[r]);
            }
        }
        // stage x_{t+1} into the other buffer (phase2 above read buffer par) — no race
        if (t + 1 < Ss) {
            short4v xs;
            #pragma unroll
            for (int i = 0; i < 4; ++i) xs[i] = f2bf(xv1[i]);
            *(short4v*)&xarr[par ^ 1][srow][scol] = xs;
        }
    }

    // final h -> out[B,H]: thread owns (rows quad*4+r, col)
    #pragma unroll
    for (int r = 0; r < 4; ++r)
        out[(size_t)(b0 + quad * 4 + r) * Hh + col] = hreg[r];
}

extern "C" void kernel_launch(void* const* d_in, const int* in_sizes, int n_in,
                              void* d_out, int out_size, void* d_ws, size_t ws_size,
                              hipStream_t stream) {
    const float* x   = (const float*)d_in[0];   // [B,S,H]
    const float* tgt = (const float*)d_in[1];   // [B,E]
    const float* Wb  = (const float*)d_in[2];   // [H,E]
    const float* Wxu = (const float*)d_in[3];
    const float* Whu = (const float*)d_in[4];
    const float* bu  = (const float*)d_in[5];
    const float* Wxr = (const float*)d_in[6];
    const float* Whr = (const float*)d_in[7];
    const float* br  = (const float*)d_in[8];
    const float* Wxc = (const float*)d_in[9];
    const float* Whc = (const float*)d_in[10];
    const float* bc  = (const float*)d_in[11];
    float* out = (float*)d_out;

    const int B = in_sizes[1] / Ee;             // 4096

    fused_kernel<<<B / BR, TPB3, 0, stream>>>(x, tgt, Wb, Wxu, Whu, bu,
                                              Wxr, Whr, br, Wxc, Whc, bc, out);
}